// Round 2
// baseline (755.952 us; speedup 1.0000x reference)
//
#include <hip/hip_runtime.h>
#include <hip/hip_bf16.h>
#include <math.h>

typedef __bf16 bf16x8 __attribute__((ext_vector_type(8)));
typedef short  s16x8  __attribute__((ext_vector_type(8)));
typedef float  f32x4  __attribute__((ext_vector_type(4)));
typedef unsigned short u16;

// ---- sizes ----
#define NN 32
#define CC 256
#define HH 56
#define WW 56
#define HP 68            // padded spatial (6 halo each side)
#define XP2_BYTES 75759616ull            // 32*68*68*256*2
#define XP2_OFF 0ull
#define WT3_OFF 75759616ull              // 200*16384 B = 3276800
#define T1_OFF  79036416ull              // 32*256*56*4 = 1835008
#define T9_OFF  80871424ull              // 32*56*56*4

__device__ inline u16 f2bf(float f) {
    unsigned int u = __builtin_bit_cast(unsigned int, f);
    u = (u + 0x7fffu + ((u >> 16) & 1u)) >> 16;   // RNE
    return (u16)u;
}

__device__ inline void gl_lds16(const char* g, char* l) {
    __builtin_amdgcn_global_load_lds(
        (const __attribute__((address_space(1))) unsigned int*)g,
        (__attribute__((address_space(3))) unsigned int*)l, 16, 0, 0);
}

// ---- zero only the halo of xp2 (interior fully written by prep_kernel) ----
// halo per n: rows {0..5,62..67} x 68 cols (816 pos) + rows 6..61 x cols
// {0..5,62..67} (672 pos) = 1488 positions x 512B.
__global__ void zero_halo(u16* __restrict__ xp2) {
    const int total = NN * 1488 * 32;           // 16B chunks
    int i = blockIdx.x * blockDim.x + threadIdx.x;
    const int stride = gridDim.x * blockDim.x;
    uint4 z; z.x = z.y = z.z = z.w = 0u;
    for (; i < total; i += stride) {
        int chunk = i & 31;
        int pid = i >> 5;
        int n = pid / 1488;
        int hp = pid - n * 1488;
        int row, col;
        if (hp < 816) { int r = hp / 68; col = hp - r * 68; row = (r < 6) ? r : r + 56; }
        else { int hq = hp - 816; int rr = hq / 12; int c12 = hq - rr * 12;
               row = 6 + rr; col = (c12 < 6) ? c12 : c12 + 56; }
        *(uint4*)((char*)xp2 + ((((size_t)n * HP + row) * HP + col) * 512) + chunk * 16) = z;
    }
}

// ---- pack w7 -> wt3 in MFMA fragment order ----
// per kn (=tap*8+chunk) block of 16KB: [wr(2)][mi(8)][lane(64)][8 cin u16]
// where c_out = wr*128+mi*16+(lane&15), cin-in-chunk = (lane>>4)*8 + j.
__global__ __launch_bounds__(256)
void pack_w(const float* __restrict__ w7, u16* __restrict__ wt3) {
    int idx = blockIdx.x * 256 + threadIdx.x;    // 256*6400 total
    int c_out = idx / 6400;
    int k = idx - c_out * 6400;
    int cin = k / 25;
    int tap = k - cin * 25;
    int kn = tap * 8 + (cin >> 5);
    int ci = cin & 31;
    int wr = c_out >> 7, mi = (c_out >> 4) & 7, mrow = c_out & 15;
    int q = ci >> 3, j = ci & 7;
    wt3[(size_t)kn * 8192 + wr * 4096 + mi * 512 + (q * 16 + mrow) * 8 + j] = f2bf(w7[idx]);
}

// ---- fused: t1 (row max) + t9 (softmax of einsum) + pack x -> xp2 bf16 ----
// reads x[n,:,h,:] ONCE; bf16 staged in LDS, written to xp2 as coalesced
// 512B-per-position bursts (old pack_x re-read x and wrote scattered 16B).
__global__ __launch_bounds__(256)
void prep_kernel(const float* __restrict__ x, const float* __restrict__ w6,
                 float* __restrict__ t1, float* __restrict__ t9,
                 u16* __restrict__ xp2) {
    const int n = blockIdx.x / HH;
    const int h = blockIdx.x % HH;
    const int wave = threadIdx.x >> 6;
    const int lane = threadIdx.x & 63;
    const bool valid = lane < WW;
    const int wl = valid ? lane : (WW - 1);
    const float* xrow = x + ((size_t)(n * CC) * HH + h) * WW;
    float accw = 0.f;
    __shared__ float sbuf[4 * 64];
    __shared__ u16 xbuf[WW * 260];   // row stride 260 u16 = 520B (8B aligned)
    for (int i = 0; i < 64; ++i) {
        int c = wave * 64 + i;
        float xv = xrow[(size_t)c * (HH * WW) + wl];
        if (valid) xbuf[lane * 260 + c] = f2bf(xv);
        float xm = valid ? xv : -INFINITY;
#pragma unroll
        for (int off = 32; off > 0; off >>= 1)
            xm = fmaxf(xm, __shfl_xor(xm, off));
        if (lane == 0) t1[(size_t)(n * CC + c) * HH + h] = xm;
        if (valid) accw += tanhf(fmaxf(xv, 0.f)) * w6[c];
    }
    sbuf[wave * 64 + lane] = accw;
    __syncthreads();
    if (wave == 0) {
        float s = sbuf[lane] + sbuf[64 + lane] + sbuf[128 + lane] + sbuf[192 + lane];
        float sm = valid ? s : -INFINITY;
        float mx = sm;
#pragma unroll
        for (int off = 32; off > 0; off >>= 1)
            mx = fmaxf(mx, __shfl_xor(mx, off));
        float e = valid ? expf(s - mx) : 0.f;
        float tot = e;
#pragma unroll
        for (int off = 32; off > 0; off >>= 1)
            tot += __shfl_xor(tot, off);
        if (valid) t9[((size_t)n * HH + h) * WW + lane] = e / tot;
    }
    // pack writeout: 56 positions x 32 oct-chunks of 16B
    u16* dst = xp2 + (((size_t)n * HP + h + 6) * HP + 6) * CC;
    for (int id = threadIdx.x; id < WW * 32; id += 256) {
        int p = id >> 5, oct = id & 31;
        const u16* srcl = xbuf + p * 260 + oct * 8;
        uint2 a = *(const uint2*)srcl;
        uint2 b = *(const uint2*)(srcl + 4);
        uint4 v; v.x = a.x; v.y = a.y; v.z = b.x; v.w = b.y;
        *(uint4*)(dst + (size_t)p * CC + oct * 8) = v;
    }
}

// ---- main: implicit GEMM, 256 couts x 256 flat-spatial per block, BK=32 ----
// 512 thr = 8 waves (2 cout-groups x 4 pos-groups), per-wave 128x64 output.
// LDS tiles stored in FRAGMENT ORDER: every frag read is base + lane*16
// (contiguous 1KB per wave -> zero bank conflicts). The permutation is baked
// into pack_w (A) and the per-lane gather source addresses (B); the
// global_load_lds destination stays linear (rule: linear dest + permuted src).
// 4 LDS buffers, counted vmcnt(8) once per K-tile, setprio around MFMA.
// XCD swizzle: 392 = 8*49, consecutive tiles (overlapping tap halos) share an
// XCD's L2.
__global__ __launch_bounds__(512, 2)
void conv_main(const char* __restrict__ xp2b, const char* __restrict__ wt3b,
               const float* __restrict__ x, const float* __restrict__ t1,
               const float* __restrict__ t9, float* __restrict__ out) {
    extern __shared__ __align__(16) char smem[];   // 4 * 32768 = 128 KiB
    const int bid = blockIdx.x;
    const int tile = (bid & 7) * 49 + (bid >> 3);   // XCD-aware swizzle
    const int tid  = threadIdx.x;
    const int wid  = tid >> 6;
    const int lane = tid & 63;
    const int m = lane & 15;
    const int q = lane >> 4;
    const int wr = wid >> 2;          // cout half: rows [wr*128, +128)
    const int wc = wid & 3;           // pos quarter: cols [wc*64, +64)
    const bool isA = wid < 4;

    // B-gather source offsets (4 x 16B per thread), fragment-order:
    // LDS slot (ni, lane) holds position (wb*64+ni*16+(lane&15)), cin chunk lane>>4.
    unsigned vb[4] = {0, 0, 0, 0};
    if (!isA) {
        const int wb = wid - 4;
#pragma unroll
        for (int i = 0; i < 4; ++i) {
            int p = tile * 256 + wb * 64 + i * 16 + m;
            int n = p / (HH * WW);
            int rem = p - n * (HH * WW);
            int hh = rem / WW;
            int ww = rem - hh * WW;
            vb[i] = ((((unsigned)n * HP + hh + 6) * HP) + ww + 6) * 512 + q * 16;
        }
    }

    // stage half a K-tile (2 gl_lds per thread). tt may exceed 199 (tail
    // dummies wrap to valid addresses; their buffers are never read).
    auto stage2 = [&](int tt, int half) {
        const int kn = (tt < 200) ? tt : (tt - 200);
        char* dst = smem + (size_t)(tt & 3) * 32768;
        if (isA) {
            const char* g = wt3b + (size_t)kn * 16384 + wid * 4096 + half * 2048 + lane * 16;
            char* d = dst + wid * 4096 + half * 2048 + lane * 16;
            gl_lds16(g, d);
            gl_lds16(g + 1024, d + 1024);
        } else {
            const int tp = kn >> 3, ch = kn & 7;
            const char* gb = xp2b +
                (ptrdiff_t)((tp / 5) * 3 - 6) * (HP * 512) +
                (ptrdiff_t)((tp % 5) * 3 - 6) * 512 + ch * 64;
            char* d = dst + 16384 + (wid - 4) * 4096 + half * 2048 + lane * 16;
            gl_lds16(gb + vb[half * 2],     d);
            gl_lds16(gb + vb[half * 2 + 1], d + 1024);
        }
    };

    f32x4 acc[8][4];
#pragma unroll
    for (int mi = 0; mi < 8; ++mi)
#pragma unroll
        for (int ni = 0; ni < 4; ++ni) {
            acc[mi][ni][0] = 0.f; acc[mi][ni][1] = 0.f;
            acc[mi][ni][2] = 0.f; acc[mi][ni][3] = 0.f;
        }

    // fragment-order read offsets: contiguous per wave, conflict-free
    const int aoff = wr * 8192 + lane * 16;            // + mi*1024 (phase1 +4096)
    const int boff = 16384 + wc * 4096 + lane * 16;    // + ni*1024

    // prologue: stage tiles 0,1,2 (12 loads/thread); wait tile 0 landed
    stage2(0, 0); stage2(0, 1);
    stage2(1, 0); stage2(1, 1);
    stage2(2, 0); stage2(2, 1);
    asm volatile("s_waitcnt vmcnt(8)" ::: "memory");
    __builtin_amdgcn_s_barrier();

    for (int t = 0; t < 200; ++t) {
        const char* bp = smem + (size_t)(t & 3) * 32768;
        bf16x8 av[4], bv[4];

        // ---- phase 0: B frags + A frags 0-3, stage half 0 of tile t+3 ----
        stage2(t + 3, 0);
#pragma unroll
        for (int ni = 0; ni < 4; ++ni)
            bv[ni] = *(const bf16x8*)(const void*)(bp + boff + ni * 1024);
#pragma unroll
        for (int mi = 0; mi < 4; ++mi)
            av[mi] = *(const bf16x8*)(const void*)(bp + aoff + mi * 1024);
        __builtin_amdgcn_s_setprio(1);
#pragma unroll
        for (int mi = 0; mi < 4; ++mi)
#pragma unroll
            for (int ni = 0; ni < 4; ++ni)
                acc[mi][ni] = __builtin_amdgcn_mfma_f32_16x16x32_bf16(
                    av[mi], bv[ni], acc[mi][ni], 0, 0, 0);
        __builtin_amdgcn_s_setprio(0);
        __builtin_amdgcn_s_barrier();

        // ---- phase 1: A frags 4-7 (bv held in regs), stage half 1 ----
        stage2(t + 3, 1);
#pragma unroll
        for (int mi = 0; mi < 4; ++mi)
            av[mi] = *(const bf16x8*)(const void*)(bp + aoff + 4096 + mi * 1024);
        __builtin_amdgcn_s_setprio(1);
#pragma unroll
        for (int mi = 0; mi < 4; ++mi)
#pragma unroll
            for (int ni = 0; ni < 4; ++ni)
                acc[mi + 4][ni] = __builtin_amdgcn_mfma_f32_16x16x32_bf16(
                    av[mi], bv[ni], acc[mi + 4][ni], 0, 0, 0);
        __builtin_amdgcn_s_setprio(0);
        // counted wait: tiles t+2, t+3 (8 gl_lds/thread) stay in flight;
        // guarantees tile t+1 fully landed before the barrier releases.
        asm volatile("s_waitcnt vmcnt(8)" ::: "memory");
        __builtin_amdgcn_s_barrier();
    }

    // epilogue: out = t1 - (t9 * roll(x,2,h) + x * t7)
#pragma unroll
    for (int ni = 0; ni < 4; ++ni) {
        const int p = tile * 256 + wc * 64 + ni * 16 + m;
        const int n = p / (HH * WW);
        const int rem = p - n * (HH * WW);
        const int h = rem / WW;
        const int w = rem - h * WW;
        const float t9v = t9[((size_t)n * HH + h) * WW + w];
        const int hprev = (h >= 2) ? (h - 2) : (h + HH - 2);
#pragma unroll
        for (int mi = 0; mi < 8; ++mi) {
            const int c = wr * 128 + mi * 16 + q * 4;
#pragma unroll
            for (int r = 0; r < 4; ++r) {
                const size_t rowi = (size_t)(n * CC + c + r) * HH;
                const float t1v = t1[rowi + h];
                const float xv = x[(rowi + h) * WW + w];
                const float xr = x[(rowi + hprev) * WW + w];
                out[(rowi + h) * WW + w] = t1v - (t9v * xr + xv * acc[mi][ni][r]);
            }
        }
    }
}

extern "C" void kernel_launch(void* const* d_in, const int* in_sizes, int n_in,
                              void* d_out, int out_size, void* d_ws, size_t ws_size,
                              hipStream_t stream) {
    const float* x  = (const float*)d_in[0];
    const float* w6 = (const float*)d_in[1];
    const float* w7 = (const float*)d_in[2];
    float* out = (float*)d_out;
    char* ws = (char*)d_ws;
    u16*   xp2 = (u16*)(ws + XP2_OFF);
    u16*   wt3 = (u16*)(ws + WT3_OFF);
    float* t1  = (float*)(ws + T1_OFF);
    float* t9  = (float*)(ws + T9_OFF);

    static bool lds_cfg_done = false;
    if (!lds_cfg_done) {
        (void)hipFuncSetAttribute((const void*)conv_main,
                                  hipFuncAttributeMaxDynamicSharedMemorySize,
                                  131072);
        lds_cfg_done = true;
    }

    zero_halo<<<dim3(1024), dim3(256), 0, stream>>>(xp2);
    pack_w<<<dim3(6400), dim3(256), 0, stream>>>(w7, wt3);
    prep_kernel<<<dim3(NN * HH), dim3(256), 0, stream>>>(x, w6, t1, t9, xp2);
    conv_main<<<dim3(392), dim3(512), 131072, stream>>>((const char*)xp2, (const char*)wt3,
                                                        x, t1, t9, out);
}

// Round 3
// 627.176 us; speedup vs baseline: 1.2053x; 1.2053x over previous
//
#include <hip/hip_runtime.h>
#include <hip/hip_bf16.h>
#include <math.h>

typedef __bf16 bf16x8 __attribute__((ext_vector_type(8)));
typedef short  s16x8  __attribute__((ext_vector_type(8)));
typedef float  f32x4  __attribute__((ext_vector_type(4)));
typedef unsigned short u16;

// ---- sizes ----
#define NN 32
#define CC 256
#define HH 56
#define WW 56
#define HP 68            // padded spatial (6 halo each side)
#define XP2_BYTES 75759616ull            // 32*68*68*256*2
#define XP2_OFF 0ull
#define WT3_OFF 75759616ull              // 200*16384 B = 3276800
#define T1_OFF  79036416ull              // 32*256*56*4 = 1835008
#define T9_OFF  80871424ull              // 32*56*56*4

__device__ inline u16 f2bf(float f) {
    unsigned int u = __builtin_bit_cast(unsigned int, f);
    u = (u + 0x7fffu + ((u >> 16) & 1u)) >> 16;   // RNE
    return (u16)u;
}

__device__ inline void gl_lds16(const char* g, char* l) {
    __builtin_amdgcn_global_load_lds(
        (const __attribute__((address_space(1))) unsigned int*)g,
        (__attribute__((address_space(3))) unsigned int*)l, 16, 0, 0);
}

// ---- zero only the halo of xp2 (interior fully written by t169p) ----
__global__ void zero_halo(u16* __restrict__ xp2) {
    const int total = NN * 1488 * 32;           // 16B chunks
    int i = blockIdx.x * blockDim.x + threadIdx.x;
    const int stride = gridDim.x * blockDim.x;
    uint4 z; z.x = z.y = z.z = z.w = 0u;
    for (; i < total; i += stride) {
        int chunk = i & 31;
        int pid = i >> 5;
        int n = pid / 1488;
        int hp = pid - n * 1488;
        int row, col;
        if (hp < 816) { int r = hp / 68; col = hp - r * 68; row = (r < 6) ? r : r + 56; }
        else { int hq = hp - 816; int rr = hq / 12; int c12 = hq - rr * 12;
               row = 6 + rr; col = (c12 < 6) ? c12 : c12 + 56; }
        *(uint4*)((char*)xp2 + ((((size_t)n * HP + row) * HP + col) * 512) + chunk * 16) = z;
    }
}

// ---- pack w7 -> wt3 in MFMA fragment order, phase-split ----
// per kn block of 16KB: [ph(2)][wr(2)][mi'(4)][lane(64)][8 cin u16]
// c_out = wr*128 + (ph*4+mi')*16 + (lane&15), cin-in-chunk = (lane>>4)*8 + j.
__global__ __launch_bounds__(256)
void pack_w(const float* __restrict__ w7, u16* __restrict__ wt3) {
    int idx = blockIdx.x * 256 + threadIdx.x;    // 256*6400 total
    int c_out = idx / 6400;
    int k = idx - c_out * 6400;
    int cin = k / 25;
    int tap = k - cin * 25;
    int kn = tap * 8 + (cin >> 5);
    int ci = cin & 31;
    int wr = c_out >> 7, mi = (c_out >> 4) & 7, mrow = c_out & 15;
    int ph = mi >> 2, mis = mi & 3;
    int q = ci >> 3, j = ci & 7;
    wt3[(size_t)kn * 8192 + ph * 4096 + wr * 2048 + mis * 512
        + (q * 16 + mrow) * 8 + j] = f2bf(w7[idx]);
}

// ---- fused: t1 (row max, unroll-4 ILP) + t9 (softmax of einsum) +
//      pack x -> xp2 bf16 (L2-hot re-read, coalesced 16B writes).
//      1KB-class LDS -> 8 blocks/CU occupancy (the r2 fused version used
//      30KB LDS + serial chains and cost ~300us; this reverts to the proven
//      t169 shape). ----
__global__ __launch_bounds__(256)
void t169p(const float* __restrict__ x, const float* __restrict__ w6,
           float* __restrict__ t1, float* __restrict__ t9,
           u16* __restrict__ xp2) {
    const int n = blockIdx.x / HH;
    const int h = blockIdx.x % HH;
    const int wave = threadIdx.x >> 6;
    const int lane = threadIdx.x & 63;
    const bool valid = lane < WW;
    const int wl = valid ? lane : (WW - 1);
    const float* xrow = x + ((size_t)(n * CC) * HH + h) * WW;
    float a0 = 0.f, a1 = 0.f, a2 = 0.f, a3 = 0.f;
    __shared__ float sbuf[4 * 64];
    for (int i0 = 0; i0 < 64; i0 += 4) {
        const int c = wave * 64 + i0;
        // 4 independent loads + 4 interleaved reduce chains (ILP)
        float x0 = xrow[(size_t)(c + 0) * (HH * WW) + wl];
        float x1 = xrow[(size_t)(c + 1) * (HH * WW) + wl];
        float x2 = xrow[(size_t)(c + 2) * (HH * WW) + wl];
        float x3 = xrow[(size_t)(c + 3) * (HH * WW) + wl];
        float m0 = valid ? x0 : -INFINITY;
        float m1 = valid ? x1 : -INFINITY;
        float m2 = valid ? x2 : -INFINITY;
        float m3 = valid ? x3 : -INFINITY;
#pragma unroll
        for (int off = 32; off > 0; off >>= 1) {
            m0 = fmaxf(m0, __shfl_xor(m0, off));
            m1 = fmaxf(m1, __shfl_xor(m1, off));
            m2 = fmaxf(m2, __shfl_xor(m2, off));
            m3 = fmaxf(m3, __shfl_xor(m3, off));
        }
        if (lane == 0) {
            t1[(size_t)(n * CC + c + 0) * HH + h] = m0;
            t1[(size_t)(n * CC + c + 1) * HH + h] = m1;
            t1[(size_t)(n * CC + c + 2) * HH + h] = m2;
            t1[(size_t)(n * CC + c + 3) * HH + h] = m3;
        }
        if (valid) {
            a0 += tanhf(fmaxf(x0, 0.f)) * w6[c + 0];
            a1 += tanhf(fmaxf(x1, 0.f)) * w6[c + 1];
            a2 += tanhf(fmaxf(x2, 0.f)) * w6[c + 2];
            a3 += tanhf(fmaxf(x3, 0.f)) * w6[c + 3];
        }
    }
    sbuf[wave * 64 + lane] = (a0 + a1) + (a2 + a3);
    __syncthreads();
    if (wave == 0) {
        float s = sbuf[lane] + sbuf[64 + lane] + sbuf[128 + lane] + sbuf[192 + lane];
        float sm = valid ? s : -INFINITY;
        float mx = sm;
#pragma unroll
        for (int off = 32; off > 0; off >>= 1)
            mx = fmaxf(mx, __shfl_xor(mx, off));
        float e = valid ? expf(s - mx) : 0.f;
        float tot = e;
#pragma unroll
        for (int off = 32; off > 0; off >>= 1)
            tot += __shfl_xor(tot, off);
        if (valid) t9[((size_t)n * HH + h) * WW + lane] = e / tot;
    }
    // pack phase: re-read the (now L2-hot) row transposed, coalesced 16B writes
    u16* dst = xp2 + (((size_t)n * HP + h + 6) * HP + 6) * CC;
    for (int id = threadIdx.x; id < WW * 32; id += 256) {
        int p = id >> 5, oct = id & 31;
        s16x8 pk;
#pragma unroll
        for (int j = 0; j < 8; ++j)
            pk[j] = (short)f2bf(xrow[(size_t)(oct * 8 + j) * (HH * WW) + p]);
        *(s16x8*)(dst + (size_t)p * CC + oct * 8) = pk;
    }
}

// ---- main: implicit GEMM, 256 couts x 256 flat-spatial per block, BK=32 ----
// 512 thr = 8 waves (2 cout-groups x 4 pos-groups), per-wave 128x64 output.
// Fragment-order LDS (every frag read = base + lane*16, conflict-free).
// A layout phase-split [ph][wr][mi'][lane][16B] so the K-tile needs ONLY ONE
// barrier: within a tile-interval, all gl_lds writes target buf (t+3)&3 ==
// (t-1)&3 while all reads target buf t&3 (disjoint); per-wave vmcnt(8) + the
// end-of-tile barrier give cross-tile ordering (4 gl_lds/wave/tile, 2 tiles
// in flight). Waves drift within the tile -> ds_read/MFMA overlap across
// waves (regs cap us at 1 block/CU, so intra-block drift is the only overlap
// mechanism available). Balanced staging: every wave stages 2KB A (L2-hot
// wt3) + 2KB B (xp2 gather) per tile.
__global__ __launch_bounds__(512, 2)
void conv_main(const char* __restrict__ xp2b, const char* __restrict__ wt3b,
               const float* __restrict__ x, const float* __restrict__ t1,
               const float* __restrict__ t9, float* __restrict__ out) {
    extern __shared__ __align__(16) char smem[];   // 4 * 32768 = 128 KiB
    const int bid = blockIdx.x;
    const int tile = (bid & 7) * 49 + (bid >> 3);   // XCD-aware swizzle
    const int tid  = threadIdx.x;
    const int wid  = tid >> 6;
    const int lane = tid & 63;
    const int m = lane & 15;
    const int q = lane >> 4;
    const int wr = wid >> 2;          // cout half: rows [wr*128, +128)
    const int wc = wid & 3;           // pos quarter: cols [wc*64, +64)

    // B staging: wave owns units {2*wid, 2*wid+1}; unit u covers positions
    // (u>>2)*64 + (u&3)*16 + m, chunk q. vb = position-dependent part.
    unsigned vb[2];
#pragma unroll
    for (int i = 0; i < 2; ++i) {
        int u = wid * 2 + i;
        int p = tile * 256 + (u >> 2) * 64 + (u & 3) * 16 + m;
        int n = p / (HH * WW);
        int rem = p - n * (HH * WW);
        int hh = rem / WW;
        int ww = rem - hh * WW;
        vb[i] = ((((unsigned)n * HP + hh + 6) * HP) + ww + 6) * 512 + q * 16;
    }
    const unsigned aoffS = wid * 1024 + lane * 16;   // A staging slot

    // tt may exceed 199 (tail dummies wrap; their buffers are never read)
    auto stageA = [&](int tt, int ph) {
        const int kn = (tt < 200) ? tt : (tt - 200);
        char* d = smem + (size_t)(tt & 3) * 32768 + ph * 8192 + aoffS;
        const char* g = wt3b + (size_t)kn * 16384 + ph * 8192 + aoffS;
        gl_lds16(g, d);
    };
    auto stageB = [&](int tt, int i) {
        const int kn = (tt < 200) ? tt : (tt - 200);
        const int tp = kn >> 3, ch = kn & 7;
        const char* gb = xp2b +
            (ptrdiff_t)((tp / 5) * 3 - 6) * (HP * 512) +
            (ptrdiff_t)((tp % 5) * 3 - 6) * 512 + ch * 64 + vb[i];
        char* d = smem + (size_t)(tt & 3) * 32768 + 16384 + (wid * 2 + i) * 1024 + lane * 16;
        gl_lds16(gb, d);
    };

    f32x4 acc[8][4];
#pragma unroll
    for (int mi = 0; mi < 8; ++mi)
#pragma unroll
        for (int ni = 0; ni < 4; ++ni) {
            acc[mi][ni][0] = 0.f; acc[mi][ni][1] = 0.f;
            acc[mi][ni][2] = 0.f; acc[mi][ni][3] = 0.f;
        }

    // fragment read offsets (contiguous per wave -> conflict-free)
    const int aoff = wr * 4096 + lane * 16;            // + ph*8192 + mi'*1024
    const int boff = 16384 + wc * 4096 + lane * 16;    // + ni*1024

    // prologue: stage tiles 0,1,2 (12 loads/thread); wait tile 0 landed
#pragma unroll
    for (int tt = 0; tt < 3; ++tt) {
        stageA(tt, 0); stageB(tt, 0);
        stageA(tt, 1); stageB(tt, 1);
    }
    asm volatile("s_waitcnt vmcnt(8)" ::: "memory");
    __builtin_amdgcn_s_barrier();

    for (int t = 0; t < 200; ++t) {
        const char* bp = smem + (size_t)(t & 3) * 32768;
        bf16x8 av[4], bv[4];

        // ---- phase 0 ----
        stageA(t + 3, 0); stageB(t + 3, 0);
#pragma unroll
        for (int ni = 0; ni < 4; ++ni)
            bv[ni] = *(const bf16x8*)(const void*)(bp + boff + ni * 1024);
#pragma unroll
        for (int mi = 0; mi < 4; ++mi)
            av[mi] = *(const bf16x8*)(const void*)(bp + aoff + mi * 1024);
        __builtin_amdgcn_s_setprio(1);
#pragma unroll
        for (int mi = 0; mi < 4; ++mi)
#pragma unroll
            for (int ni = 0; ni < 4; ++ni)
                acc[mi][ni] = __builtin_amdgcn_mfma_f32_16x16x32_bf16(
                    av[mi], bv[ni], acc[mi][ni], 0, 0, 0);
        __builtin_amdgcn_s_setprio(0);

        // ---- phase 1 (no mid barrier; bv held in regs) ----
        stageA(t + 3, 1); stageB(t + 3, 1);
#pragma unroll
        for (int mi = 0; mi < 4; ++mi)
            av[mi] = *(const bf16x8*)(const void*)(bp + aoff + 8192 + mi * 1024);
        __builtin_amdgcn_s_setprio(1);
#pragma unroll
        for (int mi = 0; mi < 4; ++mi)
#pragma unroll
            for (int ni = 0; ni < 4; ++ni)
                acc[mi + 4][ni] = __builtin_amdgcn_mfma_f32_16x16x32_bf16(
                    av[mi], bv[ni], acc[mi + 4][ni], 0, 0, 0);
        __builtin_amdgcn_s_setprio(0);
        // counted wait: tiles t+2, t+3 (8 gl_lds/thread) stay in flight;
        // guarantees tile t+1 fully landed before the barrier releases.
        asm volatile("s_waitcnt vmcnt(8)" ::: "memory");
        __builtin_amdgcn_s_barrier();
    }

    // epilogue: out = t1 - (t9 * roll(x,2,h) + x * t7)
#pragma unroll
    for (int ni = 0; ni < 4; ++ni) {
        const int p = tile * 256 + wc * 64 + ni * 16 + m;
        const int n = p / (HH * WW);
        const int rem = p - n * (HH * WW);
        const int h = rem / WW;
        const int w = rem - h * WW;
        const float t9v = t9[((size_t)n * HH + h) * WW + w];
        const int hprev = (h >= 2) ? (h - 2) : (h + HH - 2);
#pragma unroll
        for (int mi = 0; mi < 8; ++mi) {
            const int c = wr * 128 + mi * 16 + q * 4;
#pragma unroll
            for (int r = 0; r < 4; ++r) {
                const size_t rowi = (size_t)(n * CC + c + r) * HH;
                const float t1v = t1[rowi + h];
                const float xv = x[(rowi + h) * WW + w];
                const float xr = x[(rowi + hprev) * WW + w];
                out[(rowi + h) * WW + w] = t1v - (t9v * xr + xv * acc[mi][ni][r]);
            }
        }
    }
}

extern "C" void kernel_launch(void* const* d_in, const int* in_sizes, int n_in,
                              void* d_out, int out_size, void* d_ws, size_t ws_size,
                              hipStream_t stream) {
    const float* x  = (const float*)d_in[0];
    const float* w6 = (const float*)d_in[1];
    const float* w7 = (const float*)d_in[2];
    float* out = (float*)d_out;
    char* ws = (char*)d_ws;
    u16*   xp2 = (u16*)(ws + XP2_OFF);
    u16*   wt3 = (u16*)(ws + WT3_OFF);
    float* t1  = (float*)(ws + T1_OFF);
    float* t9  = (float*)(ws + T9_OFF);

    static bool lds_cfg_done = false;
    if (!lds_cfg_done) {
        (void)hipFuncSetAttribute((const void*)conv_main,
                                  hipFuncAttributeMaxDynamicSharedMemorySize,
                                  131072);
        lds_cfg_done = true;
    }

    zero_halo<<<dim3(1024), dim3(256), 0, stream>>>(xp2);
    pack_w<<<dim3(6400), dim3(256), 0, stream>>>(w7, wt3);
    t169p<<<dim3(NN * HH), dim3(256), 0, stream>>>(x, w6, t1, t9, xp2);
    conv_main<<<dim3(392), dim3(512), 131072, stream>>>((const char*)xp2, (const char*)wt3,
                                                        x, t1, t9, out);
}

// Round 4
// 618.527 us; speedup vs baseline: 1.2222x; 1.0140x over previous
//
#include <hip/hip_runtime.h>
#include <hip/hip_bf16.h>
#include <math.h>

typedef __bf16 bf16x8 __attribute__((ext_vector_type(8)));
typedef short  s16x8  __attribute__((ext_vector_type(8)));
typedef float  f32x16 __attribute__((ext_vector_type(16)));
typedef unsigned short u16;

// ---- sizes ----
#define NN 32
#define CC 256
#define HH 56
#define WW 56
#define HP 68            // padded spatial (6 halo each side)
#define XP2_BYTES 75759616ull            // 32*68*68*256*2
#define XP2_OFF 0ull
#define WT3_OFF 75759616ull              // 200*16384 B = 3276800
#define T1_OFF  79036416ull              // 32*256*56*4 = 1835008
#define T9_OFF  80871424ull              // 32*56*56*4

__device__ inline u16 f2bf(float f) {
    unsigned int u = __builtin_bit_cast(unsigned int, f);
    u = (u + 0x7fffu + ((u >> 16) & 1u)) >> 16;   // RNE
    return (u16)u;
}

__device__ inline void gl_lds16(const char* g, char* l) {
    __builtin_amdgcn_global_load_lds(
        (const __attribute__((address_space(1))) unsigned int*)g,
        (__attribute__((address_space(3))) unsigned int*)l, 16, 0, 0);
}

// ---- zero only the halo of xp2 (interior fully written by pack_x) ----
__global__ void zero_halo(u16* __restrict__ xp2) {
    const int total = NN * 1488 * 32;           // 16B chunks
    int i = blockIdx.x * blockDim.x + threadIdx.x;
    const int stride = gridDim.x * blockDim.x;
    uint4 z; z.x = z.y = z.z = z.w = 0u;
    for (; i < total; i += stride) {
        int chunk = i & 31;
        int pid = i >> 5;
        int n = pid / 1488;
        int hp = pid - n * 1488;
        int row, col;
        if (hp < 816) { int r = hp / 68; col = hp - r * 68; row = (r < 6) ? r : r + 56; }
        else { int hq = hp - 816; int rr = hq / 12; int c12 = hq - rr * 12;
               row = 6 + rr; col = (c12 < 6) ? c12 : c12 + 56; }
        *(uint4*)((char*)xp2 + ((((size_t)n * HP + row) * HP + col) * 512) + chunk * 16) = z;
    }
}

// ---- pack w7 -> wt3 in 32x32x16 MFMA fragment order ----
// per kn block of 16KB: [ks(2)][rb(8)][lane(64)][8 cin u16]
// c_out = rb*32 + (lane&31); cin-in-chunk = ks*16 + (lane>>5)*8 + j.
__global__ __launch_bounds__(256)
void pack_w(const float* __restrict__ w7, u16* __restrict__ wt3) {
    int idx = blockIdx.x * 256 + threadIdx.x;    // 256*6400 total
    int c_out = idx / 6400;
    int k = idx - c_out * 6400;
    int cin = k / 25;
    int tap = k - cin * 25;
    int kn = tap * 8 + (cin >> 5);
    int c5 = cin & 31;
    int ks = c5 >> 4, half = (c5 >> 3) & 1, j = c5 & 7;
    int lane = half * 32 + (c_out & 31);
    int rb = c_out >> 5;
    wt3[(size_t)kn * 8192 + ks * 4096 + rb * 512 + lane * 8 + j] = f2bf(w7[idx]);
}

// ---- t1 (row max, ILP4) + t9 (softmax of einsum), fast tanh ----
__global__ __launch_bounds__(256)
void t169(const float* __restrict__ x, const float* __restrict__ w6,
          float* __restrict__ t1, float* __restrict__ t9) {
    const int n = blockIdx.x / HH;
    const int h = blockIdx.x % HH;
    const int wave = threadIdx.x >> 6;
    const int lane = threadIdx.x & 63;
    const bool valid = lane < WW;
    const int wl = valid ? lane : (WW - 1);
    const float* xrow = x + ((size_t)(n * CC) * HH + h) * WW;
    float a0 = 0.f, a1 = 0.f, a2 = 0.f, a3 = 0.f;
    __shared__ float sbuf[4 * 64];
    for (int i0 = 0; i0 < 64; i0 += 4) {
        const int c = wave * 64 + i0;
        float x0 = xrow[(size_t)(c + 0) * (HH * WW) + wl];
        float x1 = xrow[(size_t)(c + 1) * (HH * WW) + wl];
        float x2 = xrow[(size_t)(c + 2) * (HH * WW) + wl];
        float x3 = xrow[(size_t)(c + 3) * (HH * WW) + wl];
        float m0 = valid ? x0 : -INFINITY;
        float m1 = valid ? x1 : -INFINITY;
        float m2 = valid ? x2 : -INFINITY;
        float m3 = valid ? x3 : -INFINITY;
#pragma unroll
        for (int off = 32; off > 0; off >>= 1) {
            m0 = fmaxf(m0, __shfl_xor(m0, off));
            m1 = fmaxf(m1, __shfl_xor(m1, off));
            m2 = fmaxf(m2, __shfl_xor(m2, off));
            m3 = fmaxf(m3, __shfl_xor(m3, off));
        }
        if (lane == 0) {
            t1[(size_t)(n * CC + c + 0) * HH + h] = m0;
            t1[(size_t)(n * CC + c + 1) * HH + h] = m1;
            t1[(size_t)(n * CC + c + 2) * HH + h] = m2;
            t1[(size_t)(n * CC + c + 3) * HH + h] = m3;
        }
        if (valid) {
            // tanh(relu(x)) = 1 - 2/(exp(2*relu(x))+1)
            float e0 = __expf(2.f * fmaxf(x0, 0.f));
            float e1 = __expf(2.f * fmaxf(x1, 0.f));
            float e2 = __expf(2.f * fmaxf(x2, 0.f));
            float e3 = __expf(2.f * fmaxf(x3, 0.f));
            a0 += (1.f - 2.f * __builtin_amdgcn_rcpf(e0 + 1.f)) * w6[c + 0];
            a1 += (1.f - 2.f * __builtin_amdgcn_rcpf(e1 + 1.f)) * w6[c + 1];
            a2 += (1.f - 2.f * __builtin_amdgcn_rcpf(e2 + 1.f)) * w6[c + 2];
            a3 += (1.f - 2.f * __builtin_amdgcn_rcpf(e3 + 1.f)) * w6[c + 3];
        }
    }
    sbuf[wave * 64 + lane] = (a0 + a1) + (a2 + a3);
    __syncthreads();
    if (wave == 0) {
        float s = sbuf[lane] + sbuf[64 + lane] + sbuf[128 + lane] + sbuf[192 + lane];
        float sm = valid ? s : -INFINITY;
        float mx = sm;
#pragma unroll
        for (int off = 32; off > 0; off >>= 1)
            mx = fmaxf(mx, __shfl_xor(mx, off));
        float e = valid ? expf(s - mx) : 0.f;
        float tot = e;
#pragma unroll
        for (int off = 32; off > 0; off >>= 1)
            tot += __shfl_xor(tot, off);
        if (valid) t9[((size_t)n * HH + h) * WW + lane] = e / tot;
    }
}

// ---- pack x -> xp2[n][h+6][w+6][c] bf16 via LDS transpose ----
// coalesced 224B row reads in, coalesced 16B chunk writes out (r3's tail did
// per-lane 4B gathers -> 64 sectors/instr; this fixes that).
__global__ __launch_bounds__(256)
void pack_x(const float* __restrict__ x, u16* __restrict__ xp2) {
    const int n = blockIdx.x / HH;
    const int h = blockIdx.x % HH;
    const int lane = threadIdx.x & 63;
    const int wid = threadIdx.x >> 6;
    __shared__ u16 xbuf[64 * 66];       // stride 66 u16: conflict-spread
    const float* xrow = x + ((size_t)(n * CC) * HH + h) * WW;
    u16* dst = xp2 + (((size_t)n * HP + h + 6) * HP + 6) * CC;
    for (int g = 0; g < 4; ++g) {
        if (g) __syncthreads();
        if (lane < WW) {
            const int c0 = g * 64 + wid * 16;
#pragma unroll
            for (int r = 0; r < 16; ++r) {
                float v = xrow[(size_t)(c0 + r) * (HH * WW) + lane];
                xbuf[(wid * 16 + r) * 66 + lane] = f2bf(v);
            }
        }
        __syncthreads();
        // writeout: 56 pos x 8 chunks of 8 u16
        for (int id = threadIdx.x; id < WW * 8; id += 256) {
            int p = id >> 3, ch8 = id & 7;
            s16x8 pk;
#pragma unroll
            for (int j = 0; j < 8; ++j)
                pk[j] = (short)xbuf[(ch8 * 8 + j) * 66 + p];
            *(s16x8*)(dst + (size_t)p * CC + g * 64 + ch8 * 8) = pk;
        }
    }
}

// ---- main: implicit GEMM, 256 couts x 256 flat-spatial per block, BK=32 ----
// 512 thr = 8 waves (2 cout-groups x 4 pos-groups), per-wave 128x64 output.
// NOW ON 32x32x16 MFMA (2495 TF path vs 2075 for 16x16x32: per-tile MFMA
// 1033 vs 1242 cy, and half the MFMA instruction count). Fragment-order LDS
// (every frag read = base + lane*16, conflict-free); per-buffer layout:
// A [ks(2)][rb(8)][1KB], B at +16K [ks(2)][cb(8)][1KB]. One barrier per
// K-tile (reads buf t&3, writes buf (t+3)&3 - disjoint); counted vmcnt(8)
// keeps 2 tiles (8 gl_lds/thread) in flight; setprio around MFMA clusters.
__global__ __launch_bounds__(512, 2)
void conv_main(const char* __restrict__ xp2b, const char* __restrict__ wt3b,
               const float* __restrict__ x, const float* __restrict__ t1,
               const float* __restrict__ t9, float* __restrict__ out) {
    extern __shared__ __align__(16) char smem[];   // 4 * 32768 = 128 KiB
    const int bid = blockIdx.x;
    const int tile = (bid & 7) * 49 + (bid >> 3);   // XCD-aware swizzle
    const int tid  = threadIdx.x;
    const int wid  = tid >> 6;
    const int lane = tid & 63;
    const int l31 = lane & 31;
    const int lhi = lane >> 5;        // 0/1: k-half within a 16-k step
    const int wr = wid >> 2;          // cout half: rows [wr*128, +128)
    const int wc = wid & 3;           // pos quarter: cols [wc*64, +64)

    // B staging: wave wid stages col-block cb=wid (32 positions), both ks.
    // LDS slot lane holds pos (cb*32 + l31), cin bytes [ks*32+lhi*16, +16).
    unsigned vb;
    {
        int p = tile * 256 + wid * 32 + l31;
        int n = p / (HH * WW);
        int rem = p - n * (HH * WW);
        int hh = rem / WW;
        int ww = rem - hh * WW;
        vb = ((((unsigned)n * HP + hh + 6) * HP) + ww + 6) * 512 + lhi * 16;
    }

    // tt may exceed 199 (tail dummies wrap; their buffers are never read)
    auto stageA = [&](int tt, int ks) {
        const int kn = (tt < 200) ? tt : (tt - 200);
        const unsigned o = ks * 8192 + wid * 1024 + lane * 16;
        char* d = smem + (size_t)(tt & 3) * 32768 + o;
        const char* g = wt3b + (size_t)kn * 16384 + o;
        gl_lds16(g, d);
    };
    auto stageB = [&](int tt, int ks) {
        const int kn = (tt < 200) ? tt : (tt - 200);
        const int tp = kn >> 3, ch = kn & 7;
        const char* gb = xp2b +
            (ptrdiff_t)((tp / 5) * 3 - 6) * (HP * 512) +
            (ptrdiff_t)((tp % 5) * 3 - 6) * 512 + ch * 64 + ks * 32 + vb;
        char* d = smem + (size_t)(tt & 3) * 32768 + 16384
                  + ks * 8192 + wid * 1024 + lane * 16;
        gl_lds16(gb, d);
    };

    f32x16 acc[4][2];
#pragma unroll
    for (int mi = 0; mi < 4; ++mi)
#pragma unroll
        for (int nb = 0; nb < 2; ++nb)
#pragma unroll
            for (int r = 0; r < 16; ++r)
                acc[mi][nb][r] = 0.f;

    // fragment read offsets (contiguous 1KB per wave -> conflict-free)
    const int aoff = wr * 4096 + lane * 16;                 // + ks*8192 + mi*1024
    const int boff = 16384 + wc * 2048 + lane * 16;         // + ks*8192 + nb*1024

    // prologue: stage tiles 0,1,2 (12 loads/thread); wait tile 0 landed
#pragma unroll
    for (int tt = 0; tt < 3; ++tt) {
        stageA(tt, 0); stageB(tt, 0);
        stageA(tt, 1); stageB(tt, 1);
    }
    asm volatile("s_waitcnt vmcnt(8)" ::: "memory");
    __builtin_amdgcn_s_barrier();

    for (int t = 0; t < 200; ++t) {
        const char* bp = smem + (size_t)(t & 3) * 32768;
        bf16x8 av[4], bv[2];

#pragma unroll
        for (int ks = 0; ks < 2; ++ks) {
            stageA(t + 3, ks); stageB(t + 3, ks);
#pragma unroll
            for (int nb = 0; nb < 2; ++nb)
                bv[nb] = *(const bf16x8*)(const void*)(bp + boff + ks * 8192 + nb * 1024);
#pragma unroll
            for (int mi = 0; mi < 4; ++mi)
                av[mi] = *(const bf16x8*)(const void*)(bp + aoff + ks * 8192 + mi * 1024);
            __builtin_amdgcn_s_setprio(1);
#pragma unroll
            for (int mi = 0; mi < 4; ++mi)
#pragma unroll
                for (int nb = 0; nb < 2; ++nb)
                    acc[mi][nb] = __builtin_amdgcn_mfma_f32_32x32x16_bf16(
                        av[mi], bv[nb], acc[mi][nb], 0, 0, 0);
            __builtin_amdgcn_s_setprio(0);
        }
        // counted wait: tiles t+2, t+3 (8 gl_lds/thread) stay in flight;
        // guarantees tile t+1 fully landed before the barrier releases.
        asm volatile("s_waitcnt vmcnt(8)" ::: "memory");
        __builtin_amdgcn_s_barrier();
    }

    // epilogue: out = t1 - (t9 * roll(x,2,h) + x * t7)
    // C/D map (m74/m101): col = lane&31, row = (r&3) + 8*(r>>2) + 4*(lane>>5)
#pragma unroll
    for (int nb = 0; nb < 2; ++nb) {
        const int p = tile * 256 + wc * 64 + nb * 32 + l31;
        const int n = p / (HH * WW);
        const int rem = p - n * (HH * WW);
        const int h = rem / WW;
        const int w = rem - h * WW;
        const float t9v = t9[((size_t)n * HH + h) * WW + w];
        const int hprev = (h >= 2) ? (h - 2) : (h + HH - 2);
#pragma unroll
        for (int mi = 0; mi < 4; ++mi) {
            const int c0 = wr * 128 + mi * 32 + 4 * lhi;
#pragma unroll
            for (int r = 0; r < 16; ++r) {
                const int c = c0 + (r & 3) + 8 * (r >> 2);
                const size_t rowi = (size_t)(n * CC + c) * HH;
                const float t1v = t1[rowi + h];
                const float xv = x[(rowi + h) * WW + w];
                const float xr = x[(rowi + hprev) * WW + w];
                out[(rowi + h) * WW + w] = t1v - (t9v * xr + xv * acc[mi][nb][r]);
            }
        }
    }
}

extern "C" void kernel_launch(void* const* d_in, const int* in_sizes, int n_in,
                              void* d_out, int out_size, void* d_ws, size_t ws_size,
                              hipStream_t stream) {
    const float* x  = (const float*)d_in[0];
    const float* w6 = (const float*)d_in[1];
    const float* w7 = (const float*)d_in[2];
    float* out = (float*)d_out;
    char* ws = (char*)d_ws;
    u16*   xp2 = (u16*)(ws + XP2_OFF);
    u16*   wt3 = (u16*)(ws + WT3_OFF);
    float* t1  = (float*)(ws + T1_OFF);
    float* t9  = (float*)(ws + T9_OFF);

    static bool lds_cfg_done = false;
    if (!lds_cfg_done) {
        (void)hipFuncSetAttribute((const void*)conv_main,
                                  hipFuncAttributeMaxDynamicSharedMemorySize,
                                  131072);
        lds_cfg_done = true;
    }

    zero_halo<<<dim3(1024), dim3(256), 0, stream>>>(xp2);
    pack_w<<<dim3(6400), dim3(256), 0, stream>>>(w7, wt3);
    t169<<<dim3(NN * HH), dim3(256), 0, stream>>>(x, w6, t1, t9);
    pack_x<<<dim3(NN * HH), dim3(256), 0, stream>>>(x, xp2);
    conv_main<<<dim3(392), dim3(512), 131072, stream>>>((const char*)xp2, (const char*)wt3,
                                                        x, t1, t9, out);
}